// Round 4
// baseline (85.519 us; speedup 1.0000x reference)
//
#include <hip/hip_runtime.h>

// CollisionLoss: pos [65536, 24, 3] fp32 -> scalar.
// Static mask: point 0 excluded, pair (2,3) excluded, diagonal excluded.
// Symmetric mask => evaluate only i<j pairs (252); num and denom both halve,
// ratio unchanged. dist<0.5 <=> sq<0.25; exp(-(dist/0.5)^2) = exp(-4*sq)
// = exp2(sq * -4/ln2) => no sqrt, v_exp_f32 fed directly.
//
// SINGLE dispatch, replay-safe (round-3 post-mortem: out[0] is only zeroed
// before the FIRST launch, so any counter kept there breaks on graph replay;
// coop launch fails under capture -- round 2). Scheme: each block writes a
// value-tagged record {s, c, magic64} to ws with release ordering. ws is
// re-poisoned by a uniform fillBuffer each iteration; a uniform <=4B fill
// pattern can never equal a 64-bit magic whose halves DIFFER, so tag
// detection is deterministic. If poison is skipped between replays, stale
// tags expose identical deterministic partials -> still correct. Block 0 is
// producer + finisher: spins (only block that waits -> no deadlock) on all
// 1024 tags, reduces, writes out[0] unconditionally every launch.

#define NPTS 24
#define BLK 256          // 4 waves; each wave owns a 63-pair row set
#define BATCHES_PER_BLK 64
#define LDS_STRIDE 73    // 73 mod 32 = 9 (odd) -> 2 lanes/bank on reads (free)

#define MAGIC 0xA5C31B7ED4F09663ULL   // halves differ: unreachable by uniform fill

typedef float v2f __attribute__((ext_vector_type(2)));

struct Rec { float s; float c; unsigned long long magic; };  // 16 B

struct Pts {
    v2f x[12], y[12], z[12];   // component g = points {2g, 2g+1}
};

#define EXP2_SCALE (-5.770780163555852f)   /* -4/ln(2) */

// Row I: pairs (I,j), j = jstart..23; jstart = I+1 except row 2 starts at 4
// (pair (2,3) excluded). Packed: 2 pairs per v_pk op.
template<int I>
__device__ __forceinline__ void row(const Pts& p, v2f& acc, int& cc) {
    constexpr int JS = (I == 2) ? 4 : (I + 1);
    constexpr int H = I >> 1;
    constexpr int L = I & 1;
    const float xi = L ? p.x[H].y : p.x[H].x;
    const float yi = L ? p.y[H].y : p.y[H].x;
    const float zi = L ? p.z[H].y : p.z[H].x;

    if constexpr (JS & 1) {          // odd start -> one scalar pair (I, JS)
        constexpr int JH = JS >> 1;  // JS odd -> .y component
        float dx = xi - p.x[JH].y;
        float dy = yi - p.y[JH].y;
        float dz = zi - p.z[JH].y;
        float sq = fmaf(dx, dx, fmaf(dy, dy, dz * dz));
        bool  w  = sq < 0.25f;
        cc += (int)__popcll(__ballot(w));
        float e = __builtin_amdgcn_exp2f(sq * EXP2_SCALE);
        acc.x += w ? e : 0.0f;
    }

    constexpr int G0 = (JS + 1) >> 1;   // first full {2g,2g+1} group
    const v2f xiv = {xi, xi}, yiv = {yi, yi}, ziv = {zi, zi};
    #pragma unroll
    for (int g = G0; g < 12; ++g) {
        v2f dx = xiv - p.x[g];
        v2f dy = yiv - p.y[g];
        v2f dz = ziv - p.z[g];
        v2f sq = __builtin_elementwise_fma(dx, dx,
                 __builtin_elementwise_fma(dy, dy, dz * dz));
        v2f m  = sq * (v2f){EXP2_SCALE, EXP2_SCALE};
        bool w0 = sq.x < 0.25f;
        bool w1 = sq.y < 0.25f;
        cc += (int)__popcll(__ballot(w0));
        cc += (int)__popcll(__ballot(w1));
        float e0 = __builtin_amdgcn_exp2f(m.x);
        float e1 = __builtin_amdgcn_exp2f(m.y);
        acc += (v2f){ w0 ? e0 : 0.0f, w1 ? e1 : 0.0f };
    }
}

__global__ __launch_bounds__(BLK, 4)
void collision_fused(const float* __restrict__ pos, Rec* __restrict__ recs,
                     float* __restrict__ out) {
    __shared__ float lds[BATCHES_PER_BLK * LDS_STRIDE];
    const int t = threadIdx.x;                        // 0..255
    const int blockBase = blockIdx.x * BATCHES_PER_BLK;

    // --- Stage 64 batches * 72 floats = 1152 float4, coalesced ---
    const float4* gp = (const float4*)pos + (size_t)blockBase * 18; // 18 f4/batch
    #pragma unroll
    for (int k = 0; k < 5; ++k) {
        int f4 = t + k * BLK;                 // 0..1279; valid < 1152
        if (f4 < 1152) {
            float4 v = gp[f4];
            int b  = f4 / 18;
            int e4 = f4 % 18;
            float* dst = &lds[b * LDS_STRIDE + e4 * 4];
            dst[0] = v.x; dst[1] = v.y; dst[2] = v.z; dst[3] = v.w;
        }
    }
    __syncthreads();

    // --- Each thread owns batch (t & 63); 4 waves each take 63 of 252 pairs ---
    Pts p;
    const float* src = &lds[(t & 63) * LDS_STRIDE];
    #pragma unroll
    for (int g = 0; g < 12; ++g) {
        p.x[g] = (v2f){src[6 * g + 0], src[6 * g + 3]};
        p.y[g] = (v2f){src[6 * g + 1], src[6 * g + 4]};
        p.z[g] = (v2f){src[6 * g + 2], src[6 * g + 5]};
    }

    v2f acc = {0.0f, 0.0f};
    int cc = 0;                 // wave-uniform collision count via ballot
    const int q = t >> 6;       // wave id -> LPT-balanced row set (63 pairs each)
    if (q == 0) {
        row< 1>(p, acc, cc); row< 8>(p, acc, cc); row<10>(p, acc, cc);
        row<15>(p, acc, cc); row<18>(p, acc, cc);
    } else if (q == 1) {
        row< 2>(p, acc, cc); row< 6>(p, acc, cc); row<11>(p, acc, cc);
        row<14>(p, acc, cc); row<19>(p, acc, cc); row<22>(p, acc, cc);
    } else if (q == 2) {
        row< 3>(p, acc, cc); row< 7>(p, acc, cc); row< 9>(p, acc, cc);
        row<16>(p, acc, cc); row<17>(p, acc, cc);
    } else {
        row< 4>(p, acc, cc); row< 5>(p, acc, cc); row<12>(p, acc, cc);
        row<13>(p, acc, cc); row<20>(p, acc, cc); row<21>(p, acc, cc);
    }

    // --- Wave reduce s; cc is already wave-uniform ---
    float s = acc.x + acc.y;
    #pragma unroll
    for (int off = 32; off >= 1; off >>= 1)
        s += __shfl_down(s, off, 64);

    __shared__ float sred[4];
    __shared__ int   cred[4];
    if ((t & 63) == 0) { sred[q] = s; cred[q] = cc; }
    __syncthreads();

    // --- Publish block record: payload, release-fence, then magic tag ---
    if (t == 0) {
        Rec* r = &recs[blockIdx.x];
        r->s = sred[0] + sred[1] + sred[2] + sred[3];
        r->c = (float)(cred[0] + cred[1] + cred[2] + cred[3]); // <=16128, exact
        __hip_atomic_store(&r->magic, (unsigned long long)MAGIC,
                           __ATOMIC_RELEASE, __HIP_MEMORY_SCOPE_AGENT);
    }
    if (blockIdx.x != 0) return;

    // --- Block 0 = finisher: spin on all 1024 tags (only waiter -> no
    //     deadlock; producers always drain), accumulate, reduce, write out ---
    float fs = 0.0f, fc = 0.0f;
    #pragma unroll
    for (int k = 0; k < 4; ++k) {
        Rec* r = &recs[t + k * 256];
        while (__hip_atomic_load(&r->magic, __ATOMIC_ACQUIRE,
                                 __HIP_MEMORY_SCOPE_AGENT)
               != (unsigned long long)MAGIC)
            __builtin_amdgcn_s_sleep(2);
        fs += __hip_atomic_load(&r->s, __ATOMIC_RELAXED,
                                __HIP_MEMORY_SCOPE_AGENT);
        fc += __hip_atomic_load(&r->c, __ATOMIC_RELAXED,
                                __HIP_MEMORY_SCOPE_AGENT);
    }
    #pragma unroll
    for (int off = 32; off >= 1; off >>= 1) {
        fs += __shfl_down(fs, off, 64);
        fc += __shfl_down(fc, off, 64);
    }
    __shared__ float sb[4], cb[4];
    if ((t & 63) == 0) { sb[t >> 6] = fs; cb[t >> 6] = fc; }
    __syncthreads();
    if (t == 0) {
        fs = sb[0] + sb[1] + sb[2] + sb[3];
        fc = cb[0] + cb[1] + cb[2] + cb[3];
        float total = (fc > 0.0f) ? (fs / fmaxf(fc, 1.0f)) : 0.0f;
        out[0] = total + 1e-6f;   // unconditional, replay-safe
    }
}

extern "C" void kernel_launch(void* const* d_in, const int* in_sizes, int n_in,
                              void* d_out, int out_size, void* d_ws, size_t ws_size,
                              hipStream_t stream) {
    const float* pos = (const float*)d_in[0];
    float* out = (float*)d_out;
    Rec* recs = (Rec*)d_ws;

    const int B = in_sizes[0] / (NPTS * 3);   // 65536
    const int nblocks = B / BATCHES_PER_BLK;  // 1024

    collision_fused<<<nblocks, BLK, 0, stream>>>(pos, recs, out);
}

// Round 5
// 70.141 us; speedup vs baseline: 1.2193x; 1.2193x over previous
//
#include <hip/hip_runtime.h>

// CollisionLoss: pos [65536, 24, 3] fp32 -> scalar.
// Static mask: point 0 excluded, pair (2,3) excluded, diagonal excluded.
// Symmetric mask => evaluate only i<j pairs (252); num and denom both halve,
// ratio unchanged. dist<0.5 <=> sq<0.25; exp(-(dist/0.5)^2) = exp(-4*sq)
// = exp2(sq * -4/ln2) => no sqrt, v_exp_f32 fed directly.
//
// SINGLE dispatch, replay-safe, FENCE-FREE (round-4 post-mortem: per-block
// agent-scope release stores / acquire polls are L2 writeback+invalidate ops
// on non-coherent-L2 CDNA4; 1024 of them cost ~15us). Each block publishes
// ONE 8-byte value: lo=bits(s), hi=bits(c+1.0f), via a RELAXED agent-scope
// atomic store (visibility at the coherence point, no cache maintenance).
// Validity is a property of the value: s < c+1 strictly => hi != lo always;
// the harness's uniform <=4B ws poison pattern has hi == lo always. The 8B
// store's atomicity replaces release/acquire ordering (payload IS the tag).
// Block 0 is producer + finisher (only waiter -> no deadlock): polls all
// 1024 words with relaxed loads, unpacks, reduces (fixed order -> bit-exact
// deterministic), writes out[0] unconditionally every launch.

#define NPTS 24
#define BLK 256          // 4 waves; each wave owns a 63-pair row set
#define BATCHES_PER_BLK 64
#define LDS_STRIDE 73    // 73 mod 32 = 9 (odd) -> 2 lanes/bank on reads (free)

typedef unsigned long long u64;
typedef float v2f __attribute__((ext_vector_type(2)));

struct Pts {
    v2f x[12], y[12], z[12];   // component g = points {2g, 2g+1}
};

#define EXP2_SCALE (-5.770780163555852f)   /* -4/ln(2) */

// Row I: pairs (I,j), j = jstart..23; jstart = I+1 except row 2 starts at 4
// (pair (2,3) excluded). Packed: 2 pairs per v_pk op.
template<int I>
__device__ __forceinline__ void row(const Pts& p, v2f& acc, int& cc) {
    constexpr int JS = (I == 2) ? 4 : (I + 1);
    constexpr int H = I >> 1;
    constexpr int L = I & 1;
    const float xi = L ? p.x[H].y : p.x[H].x;
    const float yi = L ? p.y[H].y : p.y[H].x;
    const float zi = L ? p.z[H].y : p.z[H].x;

    if constexpr (JS & 1) {          // odd start -> one scalar pair (I, JS)
        constexpr int JH = JS >> 1;  // JS odd -> .y component
        float dx = xi - p.x[JH].y;
        float dy = yi - p.y[JH].y;
        float dz = zi - p.z[JH].y;
        float sq = fmaf(dx, dx, fmaf(dy, dy, dz * dz));
        bool  w  = sq < 0.25f;
        cc += (int)__popcll(__ballot(w));
        float e = __builtin_amdgcn_exp2f(sq * EXP2_SCALE);
        acc.x += w ? e : 0.0f;
    }

    constexpr int G0 = (JS + 1) >> 1;   // first full {2g,2g+1} group
    const v2f xiv = {xi, xi}, yiv = {yi, yi}, ziv = {zi, zi};
    #pragma unroll
    for (int g = G0; g < 12; ++g) {
        v2f dx = xiv - p.x[g];
        v2f dy = yiv - p.y[g];
        v2f dz = ziv - p.z[g];
        v2f sq = __builtin_elementwise_fma(dx, dx,
                 __builtin_elementwise_fma(dy, dy, dz * dz));
        v2f m  = sq * (v2f){EXP2_SCALE, EXP2_SCALE};
        bool w0 = sq.x < 0.25f;
        bool w1 = sq.y < 0.25f;
        cc += (int)__popcll(__ballot(w0));
        cc += (int)__popcll(__ballot(w1));
        float e0 = __builtin_amdgcn_exp2f(m.x);
        float e1 = __builtin_amdgcn_exp2f(m.y);
        acc += (v2f){ w0 ? e0 : 0.0f, w1 ? e1 : 0.0f };
    }
}

__global__ __launch_bounds__(BLK, 4)
void collision_fused(const float* __restrict__ pos, u64* __restrict__ recs,
                     float* __restrict__ out) {
    __shared__ float lds[BATCHES_PER_BLK * LDS_STRIDE];
    const int t = threadIdx.x;                        // 0..255
    const int blockBase = blockIdx.x * BATCHES_PER_BLK;

    // --- Stage 64 batches * 72 floats = 1152 float4, coalesced ---
    const float4* gp = (const float4*)pos + (size_t)blockBase * 18; // 18 f4/batch
    #pragma unroll
    for (int k = 0; k < 5; ++k) {
        int f4 = t + k * BLK;                 // 0..1279; valid < 1152
        if (f4 < 1152) {
            float4 v = gp[f4];
            int b  = f4 / 18;
            int e4 = f4 % 18;
            float* dst = &lds[b * LDS_STRIDE + e4 * 4];
            dst[0] = v.x; dst[1] = v.y; dst[2] = v.z; dst[3] = v.w;
        }
    }
    __syncthreads();

    // --- Each thread owns batch (t & 63); 4 waves each take 63 of 252 pairs ---
    Pts p;
    const float* src = &lds[(t & 63) * LDS_STRIDE];
    #pragma unroll
    for (int g = 0; g < 12; ++g) {
        p.x[g] = (v2f){src[6 * g + 0], src[6 * g + 3]};
        p.y[g] = (v2f){src[6 * g + 1], src[6 * g + 4]};
        p.z[g] = (v2f){src[6 * g + 2], src[6 * g + 5]};
    }

    v2f acc = {0.0f, 0.0f};
    int cc = 0;                 // wave-uniform collision count via ballot
    const int q = t >> 6;       // wave id -> LPT-balanced row set (63 pairs each)
    if (q == 0) {
        row< 1>(p, acc, cc); row< 8>(p, acc, cc); row<10>(p, acc, cc);
        row<15>(p, acc, cc); row<18>(p, acc, cc);
    } else if (q == 1) {
        row< 2>(p, acc, cc); row< 6>(p, acc, cc); row<11>(p, acc, cc);
        row<14>(p, acc, cc); row<19>(p, acc, cc); row<22>(p, acc, cc);
    } else if (q == 2) {
        row< 3>(p, acc, cc); row< 7>(p, acc, cc); row< 9>(p, acc, cc);
        row<16>(p, acc, cc); row<17>(p, acc, cc);
    } else {
        row< 4>(p, acc, cc); row< 5>(p, acc, cc); row<12>(p, acc, cc);
        row<13>(p, acc, cc); row<20>(p, acc, cc); row<21>(p, acc, cc);
    }

    // --- Wave reduce s; cc is already wave-uniform ---
    float s = acc.x + acc.y;
    #pragma unroll
    for (int off = 32; off >= 1; off >>= 1)
        s += __shfl_down(s, off, 64);

    __shared__ float sred[4];
    __shared__ int   cred[4];
    if ((t & 63) == 0) { sred[q] = s; cred[q] = cc; }
    __syncthreads();

    // --- Publish: one 8B relaxed atomic store; payload IS the tag.
    //     lo = bits(s), hi = bits(c+1); s < c+1 strictly => hi != lo.
    //     Uniform poison fill => hi == lo. No fences, no cache maintenance. ---
    if (t == 0) {
        float sb = sred[0] + sred[1] + sred[2] + sred[3];
        float cb = (float)(cred[0] + cred[1] + cred[2] + cred[3]); // <=16128
        unsigned lo = __float_as_uint(sb);
        unsigned hi = __float_as_uint(cb + 1.0f);
        u64 rec = ((u64)hi << 32) | (u64)lo;
        __hip_atomic_store(&recs[blockIdx.x], rec,
                           __ATOMIC_RELAXED, __HIP_MEMORY_SCOPE_AGENT);
    }
    if (blockIdx.x != 0) return;

    // --- Block 0 = finisher (only waiter -> producers always drain) ---
    float fs = 0.0f, fc = 0.0f;          // fc accumulates (c_i + 1)
    #pragma unroll
    for (int k = 0; k < 4; ++k) {
        u64* rp = &recs[t + k * 256];
        u64 r;
        for (;;) {
            r = __hip_atomic_load(rp, __ATOMIC_RELAXED,
                                  __HIP_MEMORY_SCOPE_AGENT);
            if ((unsigned)(r >> 32) != (unsigned)r) break;   // valid record
            __builtin_amdgcn_s_sleep(2);
        }
        fs += __uint_as_float((unsigned)r);
        fc += __uint_as_float((unsigned)(r >> 32));
    }
    #pragma unroll
    for (int off = 32; off >= 1; off >>= 1) {
        fs += __shfl_down(fs, off, 64);
        fc += __shfl_down(fc, off, 64);
    }
    __shared__ float sb2[4], cb2[4];
    if ((t & 63) == 0) { sb2[t >> 6] = fs; cb2[t >> 6] = fc; }
    __syncthreads();
    if (t == 0) {
        fs = sb2[0] + sb2[1] + sb2[2] + sb2[3];
        fc = cb2[0] + cb2[1] + cb2[2] + cb2[3] - (float)gridDim.x; // strip +1s
        float total = (fc > 0.0f) ? (fs / fmaxf(fc, 1.0f)) : 0.0f;
        out[0] = total + 1e-6f;   // unconditional, replay-safe, deterministic
    }
}

extern "C" void kernel_launch(void* const* d_in, const int* in_sizes, int n_in,
                              void* d_out, int out_size, void* d_ws, size_t ws_size,
                              hipStream_t stream) {
    const float* pos = (const float*)d_in[0];
    float* out = (float*)d_out;
    u64* recs = (u64*)d_ws;

    const int B = in_sizes[0] / (NPTS * 3);   // 65536
    const int nblocks = B / BATCHES_PER_BLK;  // 1024

    collision_fused<<<nblocks, BLK, 0, stream>>>(pos, recs, out);
}